// Round 5
// baseline (411.639 us; speedup 1.0000x reference)
//
#include <hip/hip_runtime.h>
#include <math.h>

#define B_ 4
#define C_ 512
#define L_ 4096
#define H_ 8
#define DH_ 64
#define MLP_ 2048
#define BL_ (B_*L_)      // 16384
#define LK_ (L_+1)       // 4097

typedef _Float16 f16;
typedef _Float16 f16x8 __attribute__((ext_vector_type(8)));
typedef _Float16 f16x4 __attribute__((ext_vector_type(4)));
typedef float f32x4 __attribute__((ext_vector_type(4)));

// async global->LDS, 16B per lane (m97 pattern)
__device__ __forceinline__ void gl16(void* lds, const void* g) {
  __builtin_amdgcn_global_load_lds((const __attribute__((address_space(1))) void*)g,
                                   (__attribute__((address_space(3))) void*)lds,
                                   16, 0, 0);
}

__device__ __forceinline__ float frcp(float x) { return __builtin_amdgcn_rcpf(x); }

// ---------------------------------------------------------------- transposes
__global__ __launch_bounds__(256) void transpose_w5(const float* __restrict__ Wq,
                                                    const float* __restrict__ Wk,
                                                    const float* __restrict__ Wv,
                                                    const float* __restrict__ Wkq,
                                                    const float* __restrict__ Wkk,
                                                    f16* __restrict__ dst) {
  int z = blockIdx.z;
  const float* W = (z == 0) ? Wq : (z == 1) ? Wk : (z == 2) ? Wv : (z == 3) ? Wkq : Wkk;
  f16* Wt = dst + (size_t)z * C_ * C_;
  __shared__ float tile[32][33];
  int n0 = blockIdx.x * 32, k0 = blockIdx.y * 32;
  int tx = threadIdx.x & 31, ty = threadIdx.x >> 5;
#pragma unroll
  for (int i = 0; i < 4; ++i)
    tile[ty + i * 8][tx] = W[(size_t)(k0 + ty + i * 8) * C_ + n0 + tx];
  __syncthreads();
#pragma unroll
  for (int i = 0; i < 4; ++i)
    Wt[(size_t)(n0 + ty + i * 8) * C_ + k0 + tx] = (f16)tile[tx][ty + i * 8];
}

__global__ __launch_bounds__(256) void transpose_w(const float* __restrict__ W,
                                                   f16* __restrict__ Wt, int K, int N) {
  __shared__ float tile[32][33];
  int n0 = blockIdx.x * 32, k0 = blockIdx.y * 32;
  int tx = threadIdx.x & 31, ty = threadIdx.x >> 5;
#pragma unroll
  for (int i = 0; i < 4; ++i)
    tile[ty + i * 8][tx] = W[(size_t)(k0 + ty + i * 8) * N + n0 + tx];
  __syncthreads();
#pragma unroll
  for (int i = 0; i < 4; ++i)
    Wt[(size_t)(n0 + ty + i * 8) * K + k0 + tx] = (f16)tile[tx][ty + i * 8];
}

__global__ __launch_bounds__(256) void transpose_x(const float* __restrict__ x,
                                                   f16* __restrict__ xf) {
  __shared__ float tile[32][33];
  int b = blockIdx.z;
  int l0 = blockIdx.x * 32, c0 = blockIdx.y * 32;
  int tx = threadIdx.x & 31, ty = threadIdx.x >> 5;
#pragma unroll
  for (int i = 0; i < 4; ++i)
    tile[ty + i * 8][tx] = x[((size_t)b * C_ + c0 + ty + i * 8) * L_ + l0 + tx];
  __syncthreads();
#pragma unroll
  for (int i = 0; i < 4; ++i)
    xf[((size_t)b * L_ + l0 + ty + i * 8) * C_ + c0 + tx] = (f16)tile[tx][ty + i * 8];
}

// ------------------------------------------------- pack small param vectors
__global__ __launch_bounds__(256) void pack_params(
    const float* bq, const float* bk, const float* bv,
    const float* gq, const float* gk, const float* gv,
    const float* betaq, const float* betak, const float* betav,
    const float* bkq, const float* bkk,
    float* bqkv, float* gqkv, float* betaqkv, float* bphi) {
  int i = blockIdx.x * 256 + threadIdx.x;  // 0..1535
  int w = i >> 9, c = i & 511;
  bqkv[i]    = (w == 0 ? bq : (w == 1 ? bk : bv))[c];
  gqkv[i]    = (w == 0 ? gq : (w == 1 ? gk : gv))[c];
  betaqkv[i] = (w == 0 ? betaq : (w == 1 ? betak : betav))[c];
  if (i < 1024) bphi[i] = (i < 512) ? bkq[i] : bkk[i - 512];
}

// --------------------------------------------------- GEMM + fused LayerNorm
// Full-row blocks: BM=128, BN=512(=C_), BK=32, 512 threads, double-buffered.
// ATT=0: Y[which][row][:] = LN(A @ Wt[which]^T + bias[which]) (QKV, grid.y=which)
// ATT=1: Y[row][:] = LN( (A @ BD[b]^T) / (Bot[row][h]+1e-6) )  (attention out)
template <int ATT>
__global__ __launch_bounds__(512, 2) void gemm_ln(const f16* __restrict__ A,
                                                  const f16* __restrict__ Bt,
                                                  const float* __restrict__ bias,
                                                  const float* __restrict__ g,
                                                  const float* __restrict__ beta,
                                                  const float* __restrict__ Bot,
                                                  f16* __restrict__ Y) {
  __shared__ f16 smem[40960];              // 2 x (A 4096 + B 16384) f16 = 80 KB
  __shared__ float sred[2][4][128];        // row partial sum / sumsq per wn
  __shared__ float smu[128], srs[128];
  const int tid = threadIdx.x;             // 0..511
  const int lane = tid & 63;
  const int wv = tid >> 6;                 // 8 waves
  const int wm = wv >> 2, wn = wv & 3;     // 2 x 4 wave grid (64 x 128 each)
  const int l15 = lane & 15, q = lane >> 4;
  const int bm = blockIdx.x * 128;
  const int which = blockIdx.y;
  const int zb = ATT ? (blockIdx.x >> 5) : which;
  const f16* Bp = Bt + (size_t)zb * C_ * C_;
  if (!ATT) Y += (size_t)which * BL_ * C_;

  // staging map: thread t covers row t>>2, k-chunk slot t&3; fetched global
  // chunk = slot^(row&3)  (so frag read slot q^(row&3) yields chunk q)
  const int arow = tid >> 2;
  const int ach = (tid & 3) ^ (arow & 3);
  const f16* pa = A + (size_t)(bm + arow) * C_ + ach * 8;
  const f16* pb = Bp + (size_t)arow * C_ + ach * 8;  // + p*128 rows per inst
  const int sw = (q ^ (l15 & 3)) * 8;      // frag read swizzle (row&3 == l15&3)

  f32x4 acc[4][8] = {};

  // prologue: fill buffer 0
  gl16(smem + tid * 8, pa);
#pragma unroll
  for (int p = 0; p < 4; ++p)
    gl16(smem + 4096 + p * 4096 + tid * 8, pb + (size_t)p * 128 * C_);

  int cur = 0;
  for (int k0 = 0; k0 < C_; k0 += 32) {
    __syncthreads();                       // buf(cur) staged; buf(nxt) readers done
    if (k0 + 32 < C_) {
      int nb = (cur ^ 1) * 20480;
      gl16(smem + nb + tid * 8, pa + k0 + 32);
#pragma unroll
      for (int p = 0; p < 4; ++p)
        gl16(smem + nb + 4096 + p * 4096 + tid * 8, pb + (size_t)p * 128 * C_ + k0 + 32);
    }
    const f16* As = smem + cur * 20480;
    const f16* Bs = As + 4096;
    f16x8 af[4], bf[8];
#pragma unroll
    for (int i = 0; i < 4; ++i)
      af[i] = *(const f16x8*)&As[(wm * 64 + i * 16 + l15) * 32 + sw];
#pragma unroll
    for (int j = 0; j < 8; ++j)
      bf[j] = *(const f16x8*)&Bs[(wn * 128 + j * 16 + l15) * 32 + sw];
#pragma unroll
    for (int i = 0; i < 4; ++i)
#pragma unroll
      for (int j = 0; j < 8; ++j)
        acc[i][j] = __builtin_amdgcn_mfma_f32_16x16x32_f16(af[i], bf[j], acc[i][j], 0, 0, 0);
    cur ^= 1;
  }

  // ---- epilogue: bias / bot-divide into acc, row stats
  float bcol[8];
#pragma unroll
  for (int j = 0; j < 8; ++j)
    bcol[j] = ATT ? 0.f : bias[which * C_ + wn * 128 + j * 16 + l15];

#pragma unroll
  for (int i = 0; i < 4; ++i) {
#pragma unroll
    for (int rv = 0; rv < 4; ++rv) {
      int r = wm * 64 + i * 16 + q * 4 + rv;
      float b0 = 1.f, b1 = 1.f;
      if (ATT) {
        b0 = frcp(Bot[(size_t)(bm + r) * H_ + wn * 2] + 1e-6f);
        b1 = frcp(Bot[(size_t)(bm + r) * H_ + wn * 2 + 1] + 1e-6f);
      }
      float rs = 0.f, rq = 0.f;
#pragma unroll
      for (int j = 0; j < 8; ++j) {
        float v = acc[i][j][rv] + bcol[j];
        if (ATT) v *= (j < 4) ? b0 : b1;
        acc[i][j][rv] = v;
        rs += v; rq += v * v;
      }
#pragma unroll
      for (int m_ = 1; m_ < 16; m_ <<= 1) { rs += __shfl_xor(rs, m_); rq += __shfl_xor(rq, m_); }
      if (l15 == 0) { sred[0][wn][r] = rs; sred[1][wn][r] = rq; }
    }
  }
  __syncthreads();
  if (tid < 128) {
    float s = sred[0][0][tid] + sred[0][1][tid] + sred[0][2][tid] + sred[0][3][tid];
    float sq = sred[1][0][tid] + sred[1][1][tid] + sred[1][2][tid] + sred[1][3][tid];
    float mu = s * (1.f / C_);
    float var = sq * (1.f / C_) - mu * mu;
    smu[tid] = mu;
    srs[tid] = rsqrtf(var + 1e-5f);
  }
  __syncthreads();

  float gcol[8], btc[8];
#pragma unroll
  for (int j = 0; j < 8; ++j) {
    int col = wn * 128 + j * 16 + l15;
    gcol[j] = g[(ATT ? 0 : which * C_) + col];
    btc[j] = beta[(ATT ? 0 : which * C_) + col];
  }

  // 2 half-tiles of 64 rows through LDS ([64][524] f16), coalesced f16x8 out
#pragma unroll
  for (int hc = 0; hc < 2; ++hc) {
    if (wm == hc) {
#pragma unroll
      for (int i = 0; i < 4; ++i) {
#pragma unroll
        for (int rv = 0; rv < 4; ++rv) {
          int r = wm * 64 + i * 16 + q * 4 + rv;
          float mu = smu[r], rstd = srs[r];
          int lr = r - hc * 64;
#pragma unroll
          for (int j = 0; j < 8; ++j) {
            int col = wn * 128 + j * 16 + l15;
            float v = (acc[i][j][rv] - mu) * rstd * gcol[j] + btc[j];
            smem[lr * 524 + col] = (f16)v;
          }
        }
      }
    }
    __syncthreads();
#pragma unroll
    for (int p = 0; p < 8; ++p) {
      int idx = p * 512 + tid;
      int r = idx >> 6, cc = idx & 63;
      f16x8 o = *(const f16x8*)&smem[r * 524 + cc * 8];
      *(f16x8*)&Y[(size_t)(bm + hc * 64 + r) * C_ + cc * 8] = o;
    }
    __syncthreads();
  }
}

// ---------------------------------------------------------------- GEMM (MFMA)
// C[M,N](f16) = act(A[M,K] @ Bt[N,K]^T + bias)  -- 128x128 tiles, BK=64, dbuf
// EPI: 1 tanh(v)+1   2 gelu (tanh approx)   5 plain bias
//      6 plain bias + a-residual + transposed f32 out (+x)    [MLP-down fusion]
template <int EPI>
__global__ __launch_bounds__(256, 2) void gemm64(const f16* __restrict__ A,
                                                 const f16* __restrict__ Bt,
                                                 const float* __restrict__ bias,
                                                 f16* __restrict__ Ch,
                                                 int N, int K,
                                                 const f16* __restrict__ Ares,
                                                 const float* __restrict__ Xres,
                                                 float* __restrict__ Fout,
                                                 long long zA, long long zB,
                                                 long long zC, long long zBias) {
  __shared__ f16 smem[2 * 128 * 128];  // 64 KB: [As|Bs] x 2 buffers; epi: [128][128]
  A  += (size_t)blockIdx.z * zA;
  Bt += (size_t)blockIdx.z * zB;
  if (EPI != 6) Ch += (size_t)blockIdx.z * zC;
  bias += (size_t)blockIdx.z * zBias;

  const int tid = threadIdx.x;
  const int lane = tid & 63, wv = tid >> 6;
  const int wm = wv >> 1, wn = wv & 1;
  const int bm = blockIdx.x * 128, bn = blockIdx.y * 128;
  const int l15 = lane & 15, q = lane >> 4;

  const int srow = tid >> 3;
  const int schunk = (tid & 7) ^ (srow & 7);
  const f16* pa = A + (size_t)(bm + srow) * K + schunk * 8;
  const f16* pb = Bt + (size_t)(bn + srow) * K + schunk * 8;
  f16* la = smem + tid * 8;
  f16* lb = smem + 8192 + tid * 8;
  const int sw0 = (q ^ (lane & 7)) * 8;
  const int sw1 = ((4 + q) ^ (lane & 7)) * 8;

  f32x4 acc[4][4] = {};

#pragma unroll
  for (int p = 0; p < 4; ++p) gl16(la + p * 2048, pa + (size_t)p * 32 * K);
#pragma unroll
  for (int p = 0; p < 4; ++p) gl16(lb + p * 2048, pb + (size_t)p * 32 * K);

  int cur = 0;
  for (int k0 = 0; k0 < K; k0 += 64) {
    __syncthreads();
    const int nxt = cur ^ 1;
    if (k0 + 64 < K) {
#pragma unroll
      for (int p = 0; p < 4; ++p) gl16(la + nxt * 16384 + p * 2048, pa + (size_t)p * 32 * K + k0 + 64);
#pragma unroll
      for (int p = 0; p < 4; ++p) gl16(lb + nxt * 16384 + p * 2048, pb + (size_t)p * 32 * K + k0 + 64);
    }
    const f16* As = smem + cur * 16384;
    const f16* Bs = As + 8192;
#pragma unroll
    for (int ks = 0; ks < 2; ++ks) {
      const int sw = ks ? sw1 : sw0;
      f16x8 af[4], bf[4];
#pragma unroll
      for (int i = 0; i < 4; ++i)
        af[i] = *(const f16x8*)&As[(wm * 64 + i * 16 + l15) * 64 + sw];
#pragma unroll
      for (int j = 0; j < 4; ++j)
        bf[j] = *(const f16x8*)&Bs[(wn * 64 + j * 16 + l15) * 64 + sw];
#pragma unroll
      for (int i = 0; i < 4; ++i)
#pragma unroll
        for (int j = 0; j < 4; ++j)
          acc[i][j] = __builtin_amdgcn_mfma_f32_16x16x32_f16(af[i], bf[j], acc[i][j], 0, 0, 0);
    }
    cur = nxt;
  }

  __syncthreads();
#pragma unroll
  for (int j = 0; j < 4; ++j) {
    int lc = wn * 64 + j * 16 + l15;
    float bb = bias[bn + lc];
#pragma unroll
    for (int i = 0; i < 4; ++i) {
#pragma unroll
      for (int r = 0; r < 4; ++r) {
        int lr = wm * 64 + i * 16 + q * 4 + r;
        float v = acc[i][j][r] + bb;
        if (EPI == 1) {
          v = 2.0f * frcp(1.0f + __expf(-2.0f * v));      // tanh(v)+1
        } else if (EPI == 2) {
          v = v * frcp(1.0f + __expf(-1.5957691f * (v + 0.044715f * v * v * v)));
        }
        smem[lr * 128 + ((((lc >> 3) ^ (lr & 15)) << 3) | (lc & 7))] = (f16)v;
      }
    }
  }
  __syncthreads();

  if (EPI != 6) {
#pragma unroll
    for (int p = 0; p < 8; ++p) {
      int idx = p * 256 + tid;
      int row = idx >> 4, ch = idx & 15;
      f16x8 vv = *(const f16x8*)&smem[row * 128 + ((ch ^ (row & 15)) << 3)];
      *(f16x8*)&Ch[(size_t)(bm + row) * N + bn + ch * 8] = vv;
    }
  } else {
#pragma unroll
    for (int p = 0; p < 8; ++p) {
      int idx = p * 256 + tid;
      int row = idx >> 4, ch = idx & 15;
      f16x8 av = *(const f16x8*)&Ares[(size_t)(bm + row) * C_ + bn + ch * 8];
      f16* sp = &smem[row * 128 + ((ch ^ (row & 15)) << 3)];
      f16x8 sv = *(const f16x8*)sp;
#pragma unroll
      for (int jj = 0; jj < 8; ++jj) sv[jj] = (f16)((float)sv[jj] + (float)av[jj]);
      *(f16x8*)sp = sv;
    }
    __syncthreads();
    int c = tid & 127, lh = tid >> 7;
    int b = bm >> 12, lbase = (bm & 4095) + lh * 64;
    const float* xp = Xres + ((size_t)b * C_ + bn + c) * L_ + lbase;
    float* op = Fout + ((size_t)b * C_ + bn + c) * L_ + lbase;
    int chi = c >> 3, clo = c & 7;
#pragma unroll
    for (int s = 0; s < 16; ++s) {
      int l = lh * 64 + s * 4;
      float4 xv = *(const float4*)(xp + s * 4);
      float4 r;
      r.x = (float)smem[(l + 0) * 128 + (((chi ^ ((l + 0) & 15)) << 3) | clo)] + xv.x;
      r.y = (float)smem[(l + 1) * 128 + (((chi ^ ((l + 1) & 15)) << 3) | clo)] + xv.y;
      r.z = (float)smem[(l + 2) * 128 + (((chi ^ ((l + 2) & 15)) << 3) | clo)] + xv.z;
      r.w = (float)smem[(l + 3) * 128 + (((chi ^ ((l + 3) & 15)) << 3) | clo)] + xv.w;
      *(float4*)(op + s * 4) = r;
    }
  }
}

// ---------------------------------------------------------------- q_probe
__global__ __launch_bounds__(256) void qprobe2(const f16* __restrict__ Q,
                                               float* __restrict__ qp) {
  int blk = blockIdx.x;
  int b = blk >> 6;
  int r0 = blk * 64;
  int t = threadIdx.x;
  int c8 = (t & 63) * 8, rg = t >> 6;
  float s[8] = {0.f, 0.f, 0.f, 0.f, 0.f, 0.f, 0.f, 0.f};
#pragma unroll
  for (int i = 0; i < 16; ++i) {
    const f16* row = Q + ((size_t)r0 + rg + i * 4) * C_ + c8;
    f16x8 v = *(const f16x8*)row;
#pragma unroll
    for (int j = 0; j < 8; ++j) s[j] += (float)v[j];
  }
  __shared__ float red[4][520];
#pragma unroll
  for (int j = 0; j < 8; ++j) red[rg][c8 + j] = s[j];
  __syncthreads();
  int c = t * 2;
  float a0 = red[0][c] + red[1][c] + red[2][c] + red[3][c];
  float a1 = red[0][c + 1] + red[1][c + 1] + red[2][c + 1] + red[3][c + 1];
  atomicAdd(&qp[b * C_ + c], a0);
  atomicAdd(&qp[b * C_ + c + 1], a1);
}

// ---------------------------------------------------------------- score logits
__global__ __launch_bounds__(256) void logits_kernel(const f16* __restrict__ Kh,
                                                     const float* __restrict__ qp,
                                                     float* __restrict__ score) {
  int wv = threadIdx.x >> 6, lane = threadIdx.x & 63;
  int token = blockIdx.x * 4 + wv;
  int b = token >> 12;
  int l = token & (L_ - 1);
  const f16* row = Kh + (size_t)token * C_;
  int h = lane >> 3, j0 = (lane & 7) * 8;
  const float* qph = qp + b * C_ + h * DH_ + j0;
  float p = 0.f;
#pragma unroll
  for (int j = 0; j < 8; ++j) p += qph[j] * (float)row[h * DH_ + j0 + j];
  p += __shfl_xor(p, 1); p += __shfl_xor(p, 2); p += __shfl_xor(p, 4);
  if ((lane & 7) == 0)
    score[((size_t)b * H_ + h) * LK_ + 1 + l] = p * (1.f / L_) * 0.125f;
}

// softmax over [1+L] logits (logit[0]=0) + ksum init fused at the end
__global__ __launch_bounds__(256) void softmax_kernel(float* __restrict__ score,
                                                      const float* __restrict__ bkk,
                                                      float* __restrict__ ksum) {
  int bh = blockIdx.x, t = threadIdx.x;
  float* s = score + (size_t)bh * LK_;
  __shared__ float red[256];
  float mx = 0.f;
  for (int i = t; i < L_; i += 256) mx = fmaxf(mx, s[1 + i]);
  red[t] = mx; __syncthreads();
  for (int k = 128; k; k >>= 1) { if (t < k) red[t] = fmaxf(red[t], red[t + k]); __syncthreads(); }
  mx = red[0]; __syncthreads();
  float sum = (t == 0) ? expf(-mx) : 0.f;
  for (int i = t; i < L_; i += 256) { float e = expf(s[1 + i] - mx); s[1 + i] = e; sum += e; }
  red[t] = sum; __syncthreads();
  for (int k = 128; k; k >>= 1) { if (t < k) red[t] += red[t + k]; __syncthreads(); }
  float inv = 1.f / red[0];
  __syncthreads();
  for (int i = t; i < L_; i += 256) s[1 + i] *= inv;
  float s0 = expf(-mx) * inv;
  if (t == 0) s[0] = s0;
  if (t < 64) {
    int h = bh & 7;
    ksum[bh * 64 + t] = s0 * (tanhf(bkk[h * DH_ + t]) + 1.f);
  }
}

// ---------------------------------------------------------------- kv partials
#define PIDX(l, c) ((l) * 68 + (c))
#define AIDX(d, e) ((d) * 68 + (e) + ((((d) >> 3)) << 2))   // bank-skewed
__global__ __launch_bounds__(256, 2) void kv_part_kernel(const f16* __restrict__ phiK,
                                                         const f16* __restrict__ Vh,
                                                         const float* __restrict__ score,
                                                         float* __restrict__ kvp,
                                                         float* __restrict__ ksum) {
  __shared__ float sm0[4416];
  __shared__ float sm1[4416];
  int bh = blockIdx.y, b = bh >> 3, h = bh & 7;
  int part = blockIdx.x;
  int l0 = part * 256;
  int t = threadIdx.x, lane = t & 63, wv = t >> 6;
  int R = (lane >> 3) * 8, Cc = (lane & 7) * 8;
  float acc[8][8] = {};
  float ks[8] = {0.f, 0.f, 0.f, 0.f, 0.f, 0.f, 0.f, 0.f};

  for (int c = 0; c < 4; ++c) {
    int lc = l0 + c * 64;
    __syncthreads();
#pragma unroll
    for (int p = 0; p < 4; ++p) {
      int l = p * 16 + (t >> 4);
      int c4 = (t & 15) * 4;
      size_t grow = ((size_t)b * L_ + lc + l) * C_ + h * DH_ + c4;
      float w = score[(size_t)bh * LK_ + 1 + lc + l];
      f16x4 pk = *(const f16x4*)(phiK + grow);
      f16x4 vvv = *(const f16x4*)(Vh + grow);
      sm0[PIDX(l, c4) + 0] = w * (float)pk[0];
      sm0[PIDX(l, c4) + 1] = w * (float)pk[1];
      sm0[PIDX(l, c4) + 2] = w * (float)pk[2];
      sm0[PIDX(l, c4) + 3] = w * (float)pk[3];
      sm1[PIDX(l, c4) + 0] = (float)vvv[0];
      sm1[PIDX(l, c4) + 1] = (float)vvv[1];
      sm1[PIDX(l, c4) + 2] = (float)vvv[2];
      sm1[PIDX(l, c4) + 3] = (float)vvv[3];
    }
    __syncthreads();
#pragma unroll
    for (int i = 0; i < 16; ++i) {
      int ll = wv * 16 + i;
      float4 a0 = *(const float4*)&sm0[PIDX(ll, R)];
      float4 a1 = *(const float4*)&sm0[PIDX(ll, R + 4)];
      float4 b0 = *(const float4*)&sm1[PIDX(ll, Cc)];
      float4 b1 = *(const float4*)&sm1[PIDX(ll, Cc + 4)];
      float av[8] = {a0.x, a0.y, a0.z, a0.w, a1.x, a1.y, a1.z, a1.w};
      float bv2[8] = {b0.x, b0.y, b0.z, b0.w, b1.x, b1.y, b1.z, b1.w};
#pragma unroll
      for (int ii = 0; ii < 8; ++ii)
#pragma unroll
        for (int jj = 0; jj < 8; ++jj) acc[ii][jj] += av[ii] * bv2[jj];
      if ((lane & 7) == 0) {
#pragma unroll
        for (int ii = 0; ii < 8; ++ii) ks[ii] += av[ii];
      }
    }
  }

  __syncthreads();
  if ((lane & 7) == 0) {
#pragma unroll
    for (int i = 0; i < 8; ++i) sm1[wv * 64 + R + i] = ks[i];
  }
  for (int w = 0; w < 4; ++w) {
    if (wv == w) {
#pragma unroll
      for (int i = 0; i < 8; ++i) {
        float* p0 = &sm0[AIDX(R + i, Cc)];
        if (w == 0) {
          *(float4*)p0 = make_float4(acc[i][0], acc[i][1], acc[i][2], acc[i][3]);
          *(float4*)(p0 + 4) = make_float4(acc[i][4], acc[i][5], acc[i][6], acc[i][7]);
        } else {
          float4 o0 = *(const float4*)p0, o1 = *(const float4*)(p0 + 4);
          o0.x += acc[i][0]; o0.y += acc[i][1]; o0.z += acc[i][2]; o0.w += acc[i][3];
          o1.x += acc[i][4]; o1.y += acc[i][5]; o1.z += acc[i][6]; o1.w += acc[i][7];
          *(float4*)p0 = o0;
          *(float4*)(p0 + 4) = o1;
        }
      }
    }
    __syncthreads();
  }
  if (t < 64) {
    float s = sm1[t] + sm1[64 + t] + sm1[128 + t] + sm1[192 + t];
    atomicAdd(&ksum[bh * 64 + t], s);
  }
  float* dst = kvp + ((size_t)bh * 16 + part) * 4096;
#pragma unroll
  for (int i = 0; i < 16; ++i) {
    int idx = i * 256 + t;
    dst[idx] = sm0[AIDX(idx & 63, idx >> 6)];
  }
}

// merged: block-diag kv build (x<4096) + bottom (x>=4096)
__global__ __launch_bounds__(256) void bd_bottom(const float* __restrict__ kvp,
                                                 f16* __restrict__ BD,
                                                 const f16* __restrict__ phiQ,
                                                 const float* __restrict__ ksum,
                                                 float* __restrict__ bot) {
  if (blockIdx.x < 4096) {
    size_t i = (size_t)blockIdx.x * 256 + threadIdx.x;
    int b = (int)(i >> 18);
    int nk = (int)(i & 262143);
    int n = nk >> 9, k = nk & 511;
    int hn = n >> 6, hk = k >> 6;
    float v = 0.f;
    if (hn == hk) {
      const float* p = kvp + ((size_t)(b * H_ + hn) * 16) * 4096 + (n & 63) * 64 + (k & 63);
#pragma unroll
      for (int pp = 0; pp < 16; ++pp) v += p[pp * 4096];
    }
    BD[i] = (f16)v;
  } else {
    int wv = threadIdx.x >> 6, lane = threadIdx.x & 63;
    int token = (blockIdx.x - 4096) * 4 + wv;
    int b = token >> 12;
    const f16* row = phiQ + (size_t)token * C_;
    int h = lane >> 3, j0 = (lane & 7) * 8;
    const float* ks = ksum + (b * H_ + h) * 64 + j0;
    float p = 0.f;
#pragma unroll
    for (int j = 0; j < 8; ++j) p += ks[j] * (float)row[h * DH_ + j0 + j];
    p += __shfl_xor(p, 1); p += __shfl_xor(p, 2); p += __shfl_xor(p, 4);
    if ((lane & 7) == 0) bot[(size_t)token * H_ + h] = p;
  }
}

// ---------------------------------------------------------------- launch
extern "C" void kernel_launch(void* const* d_in, const int* in_sizes, int n_in,
                              void* d_out, int out_size, void* d_ws, size_t ws_size,
                              hipStream_t stream) {
  (void)in_sizes; (void)n_in; (void)out_size; (void)ws_size;
  const float* x     = (const float*)d_in[0];
  const float* Wq    = (const float*)d_in[1];
  const float* bq    = (const float*)d_in[2];
  const float* gq    = (const float*)d_in[3];
  const float* betaq = (const float*)d_in[4];
  const float* Wk    = (const float*)d_in[5];
  const float* bk    = (const float*)d_in[6];
  const float* gk    = (const float*)d_in[7];
  const float* betak = (const float*)d_in[8];
  const float* Wv    = (const float*)d_in[9];
  const float* bv    = (const float*)d_in[10];
  const float* gv    = (const float*)d_in[11];
  const float* betav = (const float*)d_in[12];
  const float* Wkq   = (const float*)d_in[13];
  const float* bkq   = (const float*)d_in[14];
  const float* Wkk   = (const float*)d_in[15];
  const float* bkk   = (const float*)d_in[16];
  const float* g_at  = (const float*)d_in[17];
  const float* b_at  = (const float*)d_in[18];
  const float* W1    = (const float*)d_in[19];
  const float* b1    = (const float*)d_in[20];
  const float* W2    = (const float*)d_in[21];
  const float* b2    = (const float*)d_in[22];
  float* out = (float*)d_out;

  char* ws = (char*)d_ws;
  size_t off = 0;
  auto alloc = [&](size_t bytes) -> void* {
    void* p = ws + off;
    off += (bytes + 255) & ~(size_t)255;
    return p;
  };
  f16* h1    = (f16*)alloc((size_t)BL_ * MLP_ * 2);       // 64 MB
  f16* QKVh  = (f16*)alloc((size_t)3 * BL_ * C_ * 2);     // Qh|Kh|Vh; ah reuses Qh
  f16* phiQK = (f16*)alloc((size_t)2 * BL_ * C_ * 2);     // phiQ|phiK
  f16* xf    = (f16*)alloc((size_t)BL_ * C_ * 2);
  f16* WqkvT = (f16*)alloc((size_t)3 * C_ * C_ * 2);      // Wq|Wk|Wv transposed
  f16* WkqT  = (f16*)alloc((size_t)C_ * C_ * 2);
  f16* WkkT  = (f16*)alloc((size_t)C_ * C_ * 2);
  f16* W1T   = (f16*)alloc((size_t)C_ * MLP_ * 2);
  f16* W2T   = (f16*)alloc((size_t)MLP_ * C_ * 2);
  f16* BD    = (f16*)alloc((size_t)B_ * C_ * C_ * 2);
  float* score = (float*)alloc((size_t)B_ * H_ * LK_ * 4);
  float* qp    = (float*)alloc((size_t)B_ * C_ * 4);
  float* kvp   = (float*)alloc((size_t)B_ * H_ * 16 * 4096 * 4);
  float* ksum  = (float*)alloc((size_t)B_ * H_ * DH_ * 4);
  float* bot   = (float*)alloc((size_t)BL_ * H_ * 4);
  float* bqkv    = (float*)alloc(1536 * 4);
  float* gqkv    = (float*)alloc(1536 * 4);
  float* betaqkv = (float*)alloc(1536 * 4);
  float* bphi    = (float*)alloc(1024 * 4);

  f16* Qh = QKVh;
  f16* Kh = QKVh + (size_t)BL_ * C_;
  f16* Vh = QKVh + (size_t)2 * BL_ * C_;
  f16* ah = QKVh;                    // reuse Qh region after phi/qprobe done
  f16* phiQ = phiQK;
  f16* phiK = phiQK + (size_t)BL_ * C_;

  dim3 blk(256);

  pack_params<<<6, blk, 0, stream>>>(bq, bk, bv, gq, gk, gv, betaq, betak, betav,
                                     bkq, bkk, bqkv, gqkv, betaqkv, bphi);

  transpose_w5<<<dim3(16, 16, 5), blk, 0, stream>>>(Wq, Wk, Wv, Wkq, Wkk, WqkvT);
  transpose_w<<<dim3(MLP_ / 32, C_ / 32), blk, 0, stream>>>(W1, W1T, C_, MLP_);
  transpose_w<<<dim3(C_ / 32, MLP_ / 32), blk, 0, stream>>>(W2, W2T, MLP_, C_);
  transpose_x<<<dim3(L_ / 32, C_ / 32, B_), blk, 0, stream>>>(x, xf);

  // QKV projection + per-which LayerNorm, fused -> Qh/Kh/Vh
  gemm_ln<0><<<dim3(BL_ / 128, 3), dim3(512), 0, stream>>>(
      xf, WqkvT, bqkv, gqkv, betaqkv, nullptr, QKVh);

  hipMemsetAsync(qp, 0, (size_t)B_ * C_ * 4, stream);
  qprobe2<<<BL_ / 64, blk, 0, stream>>>(Qh, qp);

  // phi projections, z-batched (z=0: Qh@Wkq->phiQ, z=1: Kh@Wkk->phiK)
  gemm64<1><<<dim3(BL_ / 128, C_ / 128, 2), blk, 0, stream>>>(
      Qh, WkqT, bphi, phiQ, C_, C_, nullptr, nullptr, nullptr,
      (long long)BL_ * C_, (long long)C_ * C_, (long long)BL_ * C_, (long long)C_);

  logits_kernel<<<BL_ / 4, blk, 0, stream>>>(Kh, qp, score);
  softmax_kernel<<<B_ * H_, blk, 0, stream>>>(score, bkk, ksum);

  kv_part_kernel<<<dim3(16, B_ * H_), blk, 0, stream>>>(phiK, Vh, score, kvp, ksum);
  bd_bottom<<<8192, blk, 0, stream>>>(kvp, BD, phiQ, ksum, bot);

  // attention out = LN( (phiQ @ blockdiag(kv)) / (phiQ.ksum + 1e-6) ) -> ah
  gemm_ln<1><<<dim3(BL_ / 128, 1), dim3(512), 0, stream>>>(
      phiQ, BD, nullptr, g_at, b_at, bot, ah);

  // MLP up
  gemm64<2><<<dim3(BL_ / 128, MLP_ / 128), blk, 0, stream>>>(
      ah, W1T, b1, h1, MLP_, C_, nullptr, nullptr, nullptr, 0, 0, 0, 0);
  // MLP down fused with residual-add + transpose + x-add -> out
  gemm64<6><<<dim3(BL_ / 128, C_ / 128), blk, 0, stream>>>(
      h1, W2T, b2, nullptr, C_, MLP_, ah, x, out, 0, 0, 0, 0);
}